// Round 7
// baseline (238.118 us; speedup 1.0000x reference)
//
#include <hip/hip_runtime.h>

// ---------------------------------------------------------------------------
// TripletContrastiveLoss on MI355X (gfx950)  — Round 19
// R18 (contiguous-panel staging) gave the first tile win since R12 (92->85.5).
// Strongest cross-round pattern: time ~ 1/(waves per CU); all pipes <25%.
// R19 levers:
//  (1) tile_mindist __launch_bounds__(256,5): VGPR 108 -> <=102 unlocks
//      5 waves/SIMD; LDS 32KB x 5 = 160KB exactly -> 20 waves/CU (+25% TLP),
//      all 1056 blocks resident in one round. Kill-signal: WRITE_SIZE spike
//      = spills.
//  (2) pipeline 4 dispatches -> 3 (memset + 2 kernels):
//      - compute_slots DELETED: slots assigned in normalize_rows via ONE
//        packed atomic per 16-row block (na | nf<<16 on cnt[0]); A-slots
//        ascend from 0, F-slots descend from 8191 (R18 panel alignment
//        preserved for any nA). 512 atomics total, drain hidden.
//      - reduce_loss FUSED into tile_mindist: ticket on cnt[1]; last block
//        reduces via identity atomicMin reads (coherent path) and writes out.
// Tile K-loop / staging / epilogue / XCD mapping: byte-identical to R18.
// ---------------------------------------------------------------------------

#define B_ROWS 8192
#define DIM    1024

typedef __bf16 bf16x8 __attribute__((ext_vector_type(8)));
typedef float  f32x4  __attribute__((ext_vector_type(4)));

__device__ __forceinline__ unsigned short f2bf_rne(float x) {
    unsigned u = __float_as_uint(x);
    unsigned r = (u + 0x7FFFu + ((u >> 16) & 1u)) >> 16;
    return (unsigned short)r;
}
__device__ __forceinline__ float bf2f(unsigned short h) {
    return __uint_as_float(((unsigned)h) << 16);
}

// Async global->LDS, 16 B per lane; contiguous 1 KiB per wave-copy.
__device__ __forceinline__ void async_copy16(const void* g, void* l) {
    __builtin_amdgcn_global_load_lds(
        (const __attribute__((address_space(1))) unsigned int*)g,
        (__attribute__((address_space(3))) unsigned int*)l,
        16, 0, 0);
}

// ---------------------------------------------------------------------------
// Kernel 1: 512 blocks x 256 thr; 16 rows/block (4 rows per wave, serial).
// Block claims slot ranges with ONE packed atomic: old = atomicAdd(cnt0,
// na | nf<<16); A-rows -> baseA+rankA (ascending), F-rows -> 8191-(baseF+
// rankF) (descending). Final cnt[0] = nA | nF<<16. Per row: L2-normalize
// fp32 -> bf16 (validated math), scatter into K-chunk-blocked G2, init
// posmin[row]=negmin[row]=0xFF, sqG/labG at slot.
// ---------------------------------------------------------------------------
__global__ __launch_bounds__(256) void normalize_rows(
    const float* __restrict__ feat, const int* __restrict__ labels,
    const int* __restrict__ dom, unsigned* __restrict__ posmin,
    unsigned* __restrict__ negmin, unsigned short* __restrict__ G,
    int* __restrict__ labG, float* __restrict__ sqG,
    unsigned* __restrict__ cnt)
{
    const int wv = threadIdx.x >> 6, lane = threadIdx.x & 63;
    const int r0 = blockIdx.x * 16;

    __shared__ int enc[16];          // A: rank | F: 0x40000000|rank
    __shared__ unsigned baseS;       // packed old counter value

    if (threadIdx.x < 16)
        enc[threadIdx.x] = (dom[r0 + threadIdx.x] == 0) ? 1 : 0;
    __syncthreads();
    if (threadIdx.x == 0) {
        int na = 0;
        #pragma unroll
        for (int i = 0; i < 16; ++i) na += enc[i];
        baseS = atomicAdd(cnt, (unsigned)na | ((unsigned)(16 - na) << 16));
        int ra = 0, rf = 0;
        #pragma unroll
        for (int i = 0; i < 16; ++i) {
            if (enc[i]) enc[i] = ra++;
            else        enc[i] = 0x40000000 | rf++;
        }
    }
    __syncthreads();
    const unsigned baseA = baseS & 0xFFFFu;
    const unsigned baseF = baseS >> 16;

    char* Gb = (char*)G;
    for (int k = 0; k < 4; ++k) {
        const int li  = wv * 4 + k;          // local row 0..15
        const int row = r0 + li;
        const int e   = enc[li];
        const int slot = (e & 0x40000000)
                       ? (8191 - (int)(baseF + (e & 0xFFFF)))
                       : (int)(baseA + e);

        const float4* src = (const float4*)(feat + (size_t)row * DIM);
        float4 v[4];
        float ss = 0.0f;
        #pragma unroll
        for (int j = 0; j < 4; ++j) {
            v[j] = src[j * 64 + lane];
            ss += v[j].x * v[j].x + v[j].y * v[j].y + v[j].z * v[j].z + v[j].w * v[j].w;
        }
        #pragma unroll
        for (int s = 32; s > 0; s >>= 1) ss += __shfl_xor(ss, s);
        const float inv = 1.0f / fmaxf(sqrtf(ss), 1e-12f);

        unsigned short ub[16];
        float ss2 = 0.0f;
        #pragma unroll
        for (int j = 0; j < 4; ++j) {
            const float f0 = v[j].x * inv, f1 = v[j].y * inv,
                        f2 = v[j].z * inv, f3 = v[j].w * inv;
            ub[j * 4 + 0] = f2bf_rne(f0); ub[j * 4 + 1] = f2bf_rne(f1);
            ub[j * 4 + 2] = f2bf_rne(f2); ub[j * 4 + 3] = f2bf_rne(f3);
            #pragma unroll
            for (int q = 0; q < 4; ++q) {
                const float fr = bf2f(ub[j * 4 + q]);
                ss2 += fr * fr;
            }
        }
        #pragma unroll
        for (int s = 32; s > 0; s >>= 1) ss2 += __shfl_xor(ss2, s);
        if (lane == 0) {
            posmin[row] = 0xFFFFFFFFu;
            negmin[row] = 0xFFFFFFFFu;
            sqG[slot]  = ss2;
            labG[slot] = labels[row];
        }
        // Blocked scatter: addr = panel*256KB + kc*8KB + (slot&127)*64 + inner
        char* rowBase = Gb + (size_t)(slot >> 7) * 262144
                           + (size_t)(slot & 127) * 64 + (lane & 7) * 8;
        const int kc0 = lane >> 3;
        #pragma unroll
        for (int j = 0; j < 4; ++j) {
            ushort4 pk;
            pk.x = ub[j * 4 + 0]; pk.y = ub[j * 4 + 1];
            pk.z = ub[j * 4 + 2]; pk.w = ub[j * 4 + 3];
            *(ushort4*)(rowBase + (size_t)(j * 8 + kc0) * 8192) = pk;
        }
    }
}

// ---------------------------------------------------------------------------
// Kernel 2: persistent 128x128 tiles, 4 waves, K=1024 in 32 steps of BK=32.
// Structure/staging/epilogue byte-identical to R18 (85.5us). Deltas:
//   * __launch_bounds__(256,5): VGPR<=102 -> 5 blocks/CU (20 waves, +25% TLP)
//   * nA = cnt[0] & 0xFFFF (packed counter)
//   * fused finalize: ticket on cnt[1]; last block reduces posmin/negmin via
//     identity atomicMin (coherent) and writes out[0].
// ---------------------------------------------------------------------------
__global__ __launch_bounds__(256, 5) void tile_mindist(
    const unsigned short* __restrict__ G, const int* __restrict__ labG,
    const float* __restrict__ sqG, unsigned* __restrict__ cnt,
    unsigned* __restrict__ posmin, unsigned* __restrict__ negmin,
    float* __restrict__ out)
{
    const int nA = (int)(cnt[0] & 0xFFFFu);
    const int nF = B_ROWS - nA;
    const int nTA = (nA + 127) >> 7;
    const int nTF = (nF + 127) >> 7;

    // [buf][A=0/F=1][128 rows x 32 shorts (64 B, unpadded)] = 32,768 B
    __shared__ __align__(16) unsigned short S[2][2][128 * 32];

    const int t = threadIdx.x;
    const int lane = t & 63, w = t >> 6;
    const int wm = w >> 1, wn = w & 1;          // wave sub-tile coords (x64)
    const int l15 = lane & 15, quad = lane >> 4;

    const int ch0 = 2 * w;                      // staging chunks 2w, 2w+1

    // Fragment read offsets (shorts), row stride 32 shorts.
    const int rdA  = (wm * 64 + l15) * 32 + quad * 8;
    const int rdF0 = ((1 - wn) * 64 + 15 - l15) * 32 + quad * 8;  // + (3-fn)*512

    const char* Gb = (const char*)G;

    // ---- per-XCD rectangle mapping (R16/R18-validated) ----
    const int xcd = blockIdx.x & 7;
    const int bx  = xcd & 1;                    // tx band (2)
    const int by  = xcd >> 1;                   // ty band (4)
    const int qa = nTA >> 1, ra = nTA & 1;
    const int sa = qa + ((bx < ra) ? 1 : 0);
    const int xa = bx * qa + ((bx < ra) ? bx : ra);
    const int qf = nTF >> 2, rf = nTF & 3;
    const int sf = qf + ((by < rf) ? 1 : 0);
    const int ya = by * qf + ((by < rf) ? by : rf);
    const int localN = sa * sf;
    const int j0 = blockIdx.x >> 3;
    const int jstride = (int)(gridDim.x >> 3);

    for (int j = j0; j < localN; j += jstride) {
        const int tx = xa + j / sf;             // slow: A-panel
        const int ty = ya + j % sf;             // fast: sweep F-band
        const int rowA0  = tx * 128;            // A slot base
        const int rowFl0 = ty * 128;            // F LOCAL base

        const char* baseA = Gb + (size_t)tx * 262144 + (size_t)(ch0 * 1024) + lane * 16;
        const char* baseF = Gb + (size_t)(63 - ty) * 262144 + (size_t)(ch0 * 1024) + lane * 16;

        f32x4 acc[4][4] = {};

        #pragma unroll
        for (int h = 0; h < 2; ++h) {
            async_copy16(baseA + h * 1024, &S[0][0][(ch0 + h) * 512]);
            async_copy16(baseF + h * 1024, &S[0][1][(ch0 + h) * 512]);
        }
        __syncthreads();                         // buf0 ready

        #pragma unroll 4
        for (int step = 0; step < 32; ++step) {
            const int cur = step & 1;
            const int nb = cur ^ 1;
            if (step < 31) {
                const size_t off = (size_t)(step + 1) * 8192;
                #pragma unroll
                for (int h = 0; h < 2; ++h) {
                    async_copy16(baseA + off + h * 1024, &S[nb][0][(ch0 + h) * 512]);
                    async_copy16(baseF + off + h * 1024, &S[nb][1][(ch0 + h) * 512]);
                }
            }

            const unsigned short* pa = &S[cur][0][rdA];
            const unsigned short* pf = &S[cur][1][rdF0];
            bf16x8 a[4], b[4];
            #pragma unroll
            for (int fm = 0; fm < 4; ++fm) a[fm] = *(const bf16x8*)(pa + fm * 512);
            #pragma unroll
            for (int fn = 0; fn < 4; ++fn) b[fn] = *(const bf16x8*)(pf + (3 - fn) * 512);
            #pragma unroll
            for (int fm = 0; fm < 4; ++fm)
                #pragma unroll
                for (int fn = 0; fn < 4; ++fn)
                    acc[fm][fn] = __builtin_amdgcn_mfma_f32_16x16x32_bf16(
                        a[fm], b[fn], acc[fm][fn], 0, 0, 0);

            __syncthreads();   // one barrier: completes nb loads, frees cur
        }

        // Epilogue. C/D layout: col = lane&15 (F), row = quad*4+reg (A).
        const float INFV = __uint_as_float(0x7f800000u);
        float sqf[4]; int lf_[4]; bool vf[4];
        #pragma unroll
        for (int fn = 0; fn < 4; ++fn) {
            const int rfl = rowFl0 + wn * 64 + fn * 16 + l15;   // F local
            vf[fn] = rfl < nF;
            const int slotF = 8191 - rfl;
            sqf[fn] = sqG[slotF];
            lf_[fn] = labG[slotF];
        }
        #pragma unroll
        for (int fm = 0; fm < 4; ++fm) {
            #pragma unroll
            for (int r = 0; r < 4; ++r) {
                const int ra2 = rowA0 + wm * 64 + fm * 16 + quad * 4 + r;
                const bool va = ra2 < nA;
                const int rac = va ? ra2 : 0;
                const float sqa = sqG[rac];
                const int la_ = labG[rac];
                float pmin = INFV, nmin = INFV;
                #pragma unroll
                for (int fn = 0; fn < 4; ++fn) {
                    const float dd = fmaxf(sqa + sqf[fn] - 2.0f * acc[fm][fn][r], 0.0f);
                    if (vf[fn]) {
                        if (la_ == lf_[fn]) pmin = fminf(pmin, dd);
                        else                nmin = fminf(nmin, dd);
                    }
                }
                #pragma unroll
                for (int s = 1; s < 16; s <<= 1) {
                    pmin = fminf(pmin, __shfl_xor(pmin, s));
                    nmin = fminf(nmin, __shfl_xor(nmin, s));
                }
                if (l15 == 0 && va) {
                    if (pmin < INFV) atomicMin(&posmin[ra2], __float_as_uint(pmin));
                    if (nmin < INFV) atomicMin(&negmin[ra2], __float_as_uint(nmin));
                }
            }
        }
        __syncthreads();   // protect LDS before next tile's prologue writes
    }

    // ---- fused finalize: last block reduces and writes out[0] ----
    unsigned* flagp = (unsigned*)&S[1][1][0];
    if (threadIdx.x == 0) {
        __threadfence();                        // release our atomicMins
        flagp[0] = (atomicAdd(&cnt[1], 1u) == (unsigned)(gridDim.x - 1)) ? 1u : 0u;
    }
    __syncthreads();
    if (flagp[0]) {
        __threadfence();                        // acquire all blocks' mins
        float tl = 0.0f, c = 0.0f;
        for (int i = threadIdx.x; i < B_ROWS; i += 256) {
            // identity atomicMin = coherent read of the final min
            const unsigned up = atomicMin(&posmin[i], 0xFFFFFFFFu);
            const unsigned un = atomicMin(&negmin[i], 0xFFFFFFFFu);
            if (up != 0xFFFFFFFFu && un != 0xFFFFFFFFu) {
                const float pd = sqrtf(__uint_as_float(up));
                const float nd = sqrtf(__uint_as_float(un));
                tl += fmaxf(pd - nd + 0.3f, 0.0f);
                c  += 1.0f;
            }
        }
        #pragma unroll
        for (int s = 32; s > 0; s >>= 1) {
            tl += __shfl_down(tl, s);
            c  += __shfl_down(c, s);
        }
        float* sb = (float*)&S[0][0][0];
        if (lane == 0) { sb[w] = tl; sb[4 + w] = c; }
        __syncthreads();
        if (threadIdx.x == 0) {
            const float s2 = sb[0] + sb[1] + sb[2] + sb[3];
            const float c2 = sb[4] + sb[5] + sb[6] + sb[7];
            out[0] = (c2 > 0.0f) ? s2 / fmaxf(c2, 1.0f) : 0.0f;
        }
    }
}

// ---------------------------------------------------------------------------
extern "C" void kernel_launch(void* const* d_in, const int* in_sizes, int n_in,
                              void* d_out, int out_size, void* d_ws, size_t ws_size,
                              hipStream_t stream) {
    const float* feat  = (const float*)d_in[0];
    const int* labels  = (const int*)d_in[1];
    const int* dom     = (const int*)d_in[2];
    float* out = (float*)d_out;

    char* ws = (char*)d_ws;
    // Workspace layout (bytes) — same footprint as validated layout.
    unsigned short* G   = (unsigned short*)(ws);                 // 16,777,216
    int*      labG      = (int*)(ws + 16777216);                 //     32,768
    float*    sqG       = (float*)(ws + 16809984);               //     32,768
    unsigned* posmin    = (unsigned*)(ws + 16842752);            //     32,768
    unsigned* negmin    = (unsigned*)(ws + 16875520);            //     32,768
    unsigned* cnt       = (unsigned*)(ws + 16908288);            //  8: packed slots, ticket
    // (old accum words unused)

    hipMemsetAsync(cnt, 0, 8, stream);          // slot counter + ticket = 0

    normalize_rows<<<B_ROWS / 16, 256, 0, stream>>>(feat, labels, dom,
                                                    posmin, negmin, G, labG,
                                                    sqG, cnt);

    // Grid 1056 = 8 XCD groups x 132; 5 blocks/CU -> all resident, one round.
    tile_mindist<<<1056, 256, 0, stream>>>(G, labG, sqG, cnt,
                                           posmin, negmin, out);
}

// Round 8
// 188.723 us; speedup vs baseline: 1.2617x; 1.2617x over previous
//
#include <hip/hip_runtime.h>

// ---------------------------------------------------------------------------
// TripletContrastiveLoss on MI355X (gfx950)  — Round 20
// R19 post-mortem: __launch_bounds__(256,5) collapsed VGPR 108->48, spilled
// the accumulators (WRITE_SIZE 7->124MB), tile 85.5->155us. 4 blocks/CU at
// VGPR~108 is the structural optimum for this tile shape.
// R20 = best-known-everything:
//   * tile_mindist K-loop/staging/epilogue = R18's 85.5us kernel EXACTLY
//     (plain launch_bounds(256)), + R19's packed-cnt / fused-finalize.
//   * ONE new variable: s_setprio(1/0) around the MFMA cluster (T5). The
//     role-diversity prerequisite is met by 4 independent blocks/CU at
//     different pipeline phases (m191-style, not m190 lockstep-null).
//   * 3-dispatch pipeline retained (memset + normalize + tile).
// ---------------------------------------------------------------------------

#define B_ROWS 8192
#define DIM    1024

typedef __bf16 bf16x8 __attribute__((ext_vector_type(8)));
typedef float  f32x4  __attribute__((ext_vector_type(4)));

__device__ __forceinline__ unsigned short f2bf_rne(float x) {
    unsigned u = __float_as_uint(x);
    unsigned r = (u + 0x7FFFu + ((u >> 16) & 1u)) >> 16;
    return (unsigned short)r;
}
__device__ __forceinline__ float bf2f(unsigned short h) {
    return __uint_as_float(((unsigned)h) << 16);
}

// Async global->LDS, 16 B per lane; contiguous 1 KiB per wave-copy.
__device__ __forceinline__ void async_copy16(const void* g, void* l) {
    __builtin_amdgcn_global_load_lds(
        (const __attribute__((address_space(1))) unsigned int*)g,
        (__attribute__((address_space(3))) unsigned int*)l,
        16, 0, 0);
}

// ---------------------------------------------------------------------------
// Kernel 1: 512 blocks x 256 thr; 16 rows/block (4 rows per wave, serial).
// Block claims slot ranges with ONE packed atomic on cnt[0] (na | nf<<16);
// A-slots ascend from 0, F-slots descend from 8191 (panel alignment for any
// nA). Per row: L2-normalize fp32 -> bf16, scatter into K-chunk-blocked G2,
// init posmin/negmin = 0xFF, sqG/labG at slot.  (R19-validated)
// ---------------------------------------------------------------------------
__global__ __launch_bounds__(256) void normalize_rows(
    const float* __restrict__ feat, const int* __restrict__ labels,
    const int* __restrict__ dom, unsigned* __restrict__ posmin,
    unsigned* __restrict__ negmin, unsigned short* __restrict__ G,
    int* __restrict__ labG, float* __restrict__ sqG,
    unsigned* __restrict__ cnt)
{
    const int wv = threadIdx.x >> 6, lane = threadIdx.x & 63;
    const int r0 = blockIdx.x * 16;

    __shared__ int enc[16];          // A: rank | F: 0x40000000|rank
    __shared__ unsigned baseS;       // packed old counter value

    if (threadIdx.x < 16)
        enc[threadIdx.x] = (dom[r0 + threadIdx.x] == 0) ? 1 : 0;
    __syncthreads();
    if (threadIdx.x == 0) {
        int na = 0;
        #pragma unroll
        for (int i = 0; i < 16; ++i) na += enc[i];
        baseS = atomicAdd(cnt, (unsigned)na | ((unsigned)(16 - na) << 16));
        int ra = 0, rf = 0;
        #pragma unroll
        for (int i = 0; i < 16; ++i) {
            if (enc[i]) enc[i] = ra++;
            else        enc[i] = 0x40000000 | rf++;
        }
    }
    __syncthreads();
    const unsigned baseA = baseS & 0xFFFFu;
    const unsigned baseF = baseS >> 16;

    char* Gb = (char*)G;
    for (int k = 0; k < 4; ++k) {
        const int li  = wv * 4 + k;          // local row 0..15
        const int row = r0 + li;
        const int e   = enc[li];
        const int slot = (e & 0x40000000)
                       ? (8191 - (int)(baseF + (e & 0xFFFF)))
                       : (int)(baseA + e);

        const float4* src = (const float4*)(feat + (size_t)row * DIM);
        float4 v[4];
        float ss = 0.0f;
        #pragma unroll
        for (int j = 0; j < 4; ++j) {
            v[j] = src[j * 64 + lane];
            ss += v[j].x * v[j].x + v[j].y * v[j].y + v[j].z * v[j].z + v[j].w * v[j].w;
        }
        #pragma unroll
        for (int s = 32; s > 0; s >>= 1) ss += __shfl_xor(ss, s);
        const float inv = 1.0f / fmaxf(sqrtf(ss), 1e-12f);

        unsigned short ub[16];
        float ss2 = 0.0f;
        #pragma unroll
        for (int j = 0; j < 4; ++j) {
            const float f0 = v[j].x * inv, f1 = v[j].y * inv,
                        f2 = v[j].z * inv, f3 = v[j].w * inv;
            ub[j * 4 + 0] = f2bf_rne(f0); ub[j * 4 + 1] = f2bf_rne(f1);
            ub[j * 4 + 2] = f2bf_rne(f2); ub[j * 4 + 3] = f2bf_rne(f3);
            #pragma unroll
            for (int q = 0; q < 4; ++q) {
                const float fr = bf2f(ub[j * 4 + q]);
                ss2 += fr * fr;
            }
        }
        #pragma unroll
        for (int s = 32; s > 0; s >>= 1) ss2 += __shfl_xor(ss2, s);
        if (lane == 0) {
            posmin[row] = 0xFFFFFFFFu;
            negmin[row] = 0xFFFFFFFFu;
            sqG[slot]  = ss2;
            labG[slot] = labels[row];
        }
        // Blocked scatter: addr = panel*256KB + kc*8KB + (slot&127)*64 + inner
        char* rowBase = Gb + (size_t)(slot >> 7) * 262144
                           + (size_t)(slot & 127) * 64 + (lane & 7) * 8;
        const int kc0 = lane >> 3;
        #pragma unroll
        for (int j = 0; j < 4; ++j) {
            ushort4 pk;
            pk.x = ub[j * 4 + 0]; pk.y = ub[j * 4 + 1];
            pk.z = ub[j * 4 + 2]; pk.w = ub[j * 4 + 3];
            *(ushort4*)(rowBase + (size_t)(j * 8 + kc0) * 8192) = pk;
        }
    }
}

// ---------------------------------------------------------------------------
// Kernel 2: persistent 128x128 tiles, 4 waves, K=1024 in 32 steps of BK=32.
// Body = R18's 85.5us kernel (contiguous blocked-panel staging, descending-F
// reversal, XCD rectangles). Plain __launch_bounds__(256): VGPR ~108,
// 4 blocks/CU — the measured optimum. New: s_setprio around MFMAs (T5;
// cross-block phase diversity on each CU).
// Fused finalize (R19-validated): ticket on cnt[1]; last block reduces via
// identity atomicMin reads and writes out[0].
// ---------------------------------------------------------------------------
__global__ __launch_bounds__(256) void tile_mindist(
    const unsigned short* __restrict__ G, const int* __restrict__ labG,
    const float* __restrict__ sqG, unsigned* __restrict__ cnt,
    unsigned* __restrict__ posmin, unsigned* __restrict__ negmin,
    float* __restrict__ out)
{
    const int nA = (int)(cnt[0] & 0xFFFFu);
    const int nF = B_ROWS - nA;
    const int nTA = (nA + 127) >> 7;
    const int nTF = (nF + 127) >> 7;

    // [buf][A=0/F=1][128 rows x 32 shorts (64 B, unpadded)] = 32,768 B
    __shared__ __align__(16) unsigned short S[2][2][128 * 32];

    const int t = threadIdx.x;
    const int lane = t & 63, w = t >> 6;
    const int wm = w >> 1, wn = w & 1;          // wave sub-tile coords (x64)
    const int l15 = lane & 15, quad = lane >> 4;

    const int ch0 = 2 * w;                      // staging chunks 2w, 2w+1

    // Fragment read offsets (shorts), row stride 32 shorts.
    const int rdA  = (wm * 64 + l15) * 32 + quad * 8;
    const int rdF0 = ((1 - wn) * 64 + 15 - l15) * 32 + quad * 8;  // + (3-fn)*512

    const char* Gb = (const char*)G;

    // ---- per-XCD rectangle mapping (R16/R18-validated) ----
    const int xcd = blockIdx.x & 7;
    const int bx  = xcd & 1;                    // tx band (2)
    const int by  = xcd >> 1;                   // ty band (4)
    const int qa = nTA >> 1, ra = nTA & 1;
    const int sa = qa + ((bx < ra) ? 1 : 0);
    const int xa = bx * qa + ((bx < ra) ? bx : ra);
    const int qf = nTF >> 2, rf = nTF & 3;
    const int sf = qf + ((by < rf) ? 1 : 0);
    const int ya = by * qf + ((by < rf) ? by : rf);
    const int localN = sa * sf;
    const int j0 = blockIdx.x >> 3;
    const int jstride = (int)(gridDim.x >> 3);

    for (int j = j0; j < localN; j += jstride) {
        const int tx = xa + j / sf;             // slow: A-panel
        const int ty = ya + j % sf;             // fast: sweep F-band
        const int rowA0  = tx * 128;            // A slot base
        const int rowFl0 = ty * 128;            // F LOCAL base

        const char* baseA = Gb + (size_t)tx * 262144 + (size_t)(ch0 * 1024) + lane * 16;
        const char* baseF = Gb + (size_t)(63 - ty) * 262144 + (size_t)(ch0 * 1024) + lane * 16;

        f32x4 acc[4][4] = {};

        #pragma unroll
        for (int h = 0; h < 2; ++h) {
            async_copy16(baseA + h * 1024, &S[0][0][(ch0 + h) * 512]);
            async_copy16(baseF + h * 1024, &S[0][1][(ch0 + h) * 512]);
        }
        __syncthreads();                         // buf0 ready

        #pragma unroll 4
        for (int step = 0; step < 32; ++step) {
            const int cur = step & 1;
            const int nb = cur ^ 1;
            if (step < 31) {
                const size_t off = (size_t)(step + 1) * 8192;
                #pragma unroll
                for (int h = 0; h < 2; ++h) {
                    async_copy16(baseA + off + h * 1024, &S[nb][0][(ch0 + h) * 512]);
                    async_copy16(baseF + off + h * 1024, &S[nb][1][(ch0 + h) * 512]);
                }
            }

            const unsigned short* pa = &S[cur][0][rdA];
            const unsigned short* pf = &S[cur][1][rdF0];
            bf16x8 a[4], b[4];
            #pragma unroll
            for (int fm = 0; fm < 4; ++fm) a[fm] = *(const bf16x8*)(pa + fm * 512);
            #pragma unroll
            for (int fn = 0; fn < 4; ++fn) b[fn] = *(const bf16x8*)(pf + (3 - fn) * 512);

            __builtin_amdgcn_s_setprio(1);       // T5: favor the MFMA cluster
            #pragma unroll
            for (int fm = 0; fm < 4; ++fm)
                #pragma unroll
                for (int fn = 0; fn < 4; ++fn)
                    acc[fm][fn] = __builtin_amdgcn_mfma_f32_16x16x32_bf16(
                        a[fm], b[fn], acc[fm][fn], 0, 0, 0);
            __builtin_amdgcn_s_setprio(0);

            __syncthreads();   // one barrier: completes nb loads, frees cur
        }

        // Epilogue. C/D layout: col = lane&15 (F), row = quad*4+reg (A).
        const float INFV = __uint_as_float(0x7f800000u);
        float sqf[4]; int lf_[4]; bool vf[4];
        #pragma unroll
        for (int fn = 0; fn < 4; ++fn) {
            const int rfl = rowFl0 + wn * 64 + fn * 16 + l15;   // F local
            vf[fn] = rfl < nF;
            const int slotF = 8191 - rfl;
            sqf[fn] = sqG[slotF];
            lf_[fn] = labG[slotF];
        }
        #pragma unroll
        for (int fm = 0; fm < 4; ++fm) {
            #pragma unroll
            for (int r = 0; r < 4; ++r) {
                const int ra2 = rowA0 + wm * 64 + fm * 16 + quad * 4 + r;
                const bool va = ra2 < nA;
                const int rac = va ? ra2 : 0;
                const float sqa = sqG[rac];
                const int la_ = labG[rac];
                float pmin = INFV, nmin = INFV;
                #pragma unroll
                for (int fn = 0; fn < 4; ++fn) {
                    const float dd = fmaxf(sqa + sqf[fn] - 2.0f * acc[fm][fn][r], 0.0f);
                    if (vf[fn]) {
                        if (la_ == lf_[fn]) pmin = fminf(pmin, dd);
                        else                nmin = fminf(nmin, dd);
                    }
                }
                #pragma unroll
                for (int s = 1; s < 16; s <<= 1) {
                    pmin = fminf(pmin, __shfl_xor(pmin, s));
                    nmin = fminf(nmin, __shfl_xor(nmin, s));
                }
                if (l15 == 0 && va) {
                    if (pmin < INFV) atomicMin(&posmin[ra2], __float_as_uint(pmin));
                    if (nmin < INFV) atomicMin(&negmin[ra2], __float_as_uint(nmin));
                }
            }
        }
        __syncthreads();   // protect LDS before next tile's prologue writes
    }

    // ---- fused finalize: last block reduces and writes out[0] ----
    unsigned* flagp = (unsigned*)&S[1][1][0];
    if (threadIdx.x == 0) {
        __threadfence();                        // release our atomicMins
        flagp[0] = (atomicAdd(&cnt[1], 1u) == (unsigned)(gridDim.x - 1)) ? 1u : 0u;
    }
    __syncthreads();
    if (flagp[0]) {
        __threadfence();                        // acquire all blocks' mins
        float tl = 0.0f, c = 0.0f;
        for (int i = threadIdx.x; i < B_ROWS; i += 256) {
            // identity atomicMin = coherent read of the final min
            const unsigned up = atomicMin(&posmin[i], 0xFFFFFFFFu);
            const unsigned un = atomicMin(&negmin[i], 0xFFFFFFFFu);
            if (up != 0xFFFFFFFFu && un != 0xFFFFFFFFu) {
                const float pd = sqrtf(__uint_as_float(up));
                const float nd = sqrtf(__uint_as_float(un));
                tl += fmaxf(pd - nd + 0.3f, 0.0f);
                c  += 1.0f;
            }
        }
        #pragma unroll
        for (int s = 32; s > 0; s >>= 1) {
            tl += __shfl_down(tl, s);
            c  += __shfl_down(c, s);
        }
        float* sb = (float*)&S[0][0][0];
        if (lane == 0) { sb[w] = tl; sb[4 + w] = c; }
        __syncthreads();
        if (threadIdx.x == 0) {
            const float s2 = sb[0] + sb[1] + sb[2] + sb[3];
            const float c2 = sb[4] + sb[5] + sb[6] + sb[7];
            out[0] = (c2 > 0.0f) ? s2 / fmaxf(c2, 1.0f) : 0.0f;
        }
    }
}

// ---------------------------------------------------------------------------
extern "C" void kernel_launch(void* const* d_in, const int* in_sizes, int n_in,
                              void* d_out, int out_size, void* d_ws, size_t ws_size,
                              hipStream_t stream) {
    const float* feat  = (const float*)d_in[0];
    const int* labels  = (const int*)d_in[1];
    const int* dom     = (const int*)d_in[2];
    float* out = (float*)d_out;

    char* ws = (char*)d_ws;
    // Workspace layout (bytes) — same footprint as validated layout.
    unsigned short* G   = (unsigned short*)(ws);                 // 16,777,216
    int*      labG      = (int*)(ws + 16777216);                 //     32,768
    float*    sqG       = (float*)(ws + 16809984);               //     32,768
    unsigned* posmin    = (unsigned*)(ws + 16842752);            //     32,768
    unsigned* negmin    = (unsigned*)(ws + 16875520);            //     32,768
    unsigned* cnt       = (unsigned*)(ws + 16908288);            //  8: packed slots, ticket

    hipMemsetAsync(cnt, 0, 8, stream);          // slot counter + ticket = 0

    normalize_rows<<<B_ROWS / 16, 256, 0, stream>>>(feat, labels, dom,
                                                    posmin, negmin, G, labG,
                                                    sqG, cnt);

    // Grid 1056 = 8 XCD groups x 132; 4 blocks/CU (VGPR ~108).
    tile_mindist<<<1056, 256, 0, stream>>>(G, labG, sqG, cnt,
                                           posmin, negmin, out);
}

// Round 9
// 165.785 us; speedup vs baseline: 1.4363x; 1.1384x over previous
//
#include <hip/hip_runtime.h>

// ---------------------------------------------------------------------------
// TripletContrastiveLoss on MI355X (gfx950)  — Round 21
// R20 post-mortem: setprio around MFMA perturbed codegen (VGPR 108->128,
// ds_read/MFMA interleave destroyed) -> tile 85.5->109.6us. T5 confirmed
// null-to-harmful in barrier-lockstep GEMM (m190). Dropped.
// Cross-round model now fits ALL data: per-CU L2 streaming BW on staged
// operand bytes (blocks/CU x 16KB per step-service vs ~45-56 B/cyc/CU) is
// the binding tier — not HBM (R16), not bank conflicts (R17), not occupancy
// depth (R13/R14), not txn count alone (R18 = the one win, -7%).
// R21 = exact restore of the verified champion (R18, 165.2us total,
// tile 85.5us): contiguous K-chunk-blocked panels, descending-F slots,
// XCD rectangle mapping, 4-dispatch pipeline. No new variables.
// ---------------------------------------------------------------------------

#define B_ROWS 8192
#define DIM    1024

typedef __bf16 bf16x8 __attribute__((ext_vector_type(8)));
typedef float  f32x4  __attribute__((ext_vector_type(4)));

__device__ __forceinline__ unsigned short f2bf_rne(float x) {
    unsigned u = __float_as_uint(x);
    unsigned r = (u + 0x7FFFu + ((u >> 16) & 1u)) >> 16;
    return (unsigned short)r;
}
__device__ __forceinline__ float bf2f(unsigned short h) {
    return __uint_as_float(((unsigned)h) << 16);
}

// Async global->LDS, 16 B per lane. LDS dest is wave-uniform base; HW places
// lane i at base + 16*i. With a CONTIGUOUS 1 KiB source, the LDS image is
// 16 rows x 64 B row-major — identical to the consume-side layout.
__device__ __forceinline__ void async_copy16(const void* g, void* l) {
    __builtin_amdgcn_global_load_lds(
        (const __attribute__((address_space(1))) unsigned int*)g,
        (__attribute__((address_space(3))) unsigned int*)l,
        16, 0, 0);
}

// ---------------------------------------------------------------------------
// Kernel 0: slot assignment + accum/ticket init. A rows -> slots ascending
// from 0; F rows -> slots DESCENDING from 8191 (panel-aligned F tiles for
// any nA). Any bijection is valid; downstream agrees on the mapping.
// ---------------------------------------------------------------------------
__global__ __launch_bounds__(256) void compute_slots(
    const int* __restrict__ dom, int* __restrict__ slotOf,
    unsigned* __restrict__ cnt, float* __restrict__ accum)
{
    __shared__ int cnts[256];
    __shared__ int base[257];
    const int t = threadIdx.x;

    if (t == 0) {
        cnt[1] = 0u;
        accum[0] = 0.0f;
        accum[1] = 0.0f;
    }

    unsigned mask = 0u; int c = 0;
    #pragma unroll
    for (int i = 0; i < 32; ++i) {
        const int isA = (dom[t + 256 * i] == 0) ? 1 : 0;
        mask |= ((unsigned)isA) << i;
        c += isA;
    }
    cnts[t] = c;
    __syncthreads();
    if (t < 64) {
        const int c0 = cnts[4 * t + 0], c1 = cnts[4 * t + 1];
        const int c2 = cnts[4 * t + 2], c3 = cnts[4 * t + 3];
        const int s4 = c0 + c1 + c2 + c3;
        int sc = s4;
        #pragma unroll
        for (int d = 1; d < 64; d <<= 1) {
            const int o = __shfl_up(sc, d);
            if (t >= d) sc += o;
        }
        const int b = sc - s4;
        base[4 * t + 0] = b;
        base[4 * t + 1] = b + c0;
        base[4 * t + 2] = b + c0 + c1;
        base[4 * t + 3] = b + c0 + c1 + c2;
        if (t == 63) { base[256] = sc; cnt[0] = (unsigned)sc; }
    }
    __syncthreads();
    int aB = base[t];                 // A slots before this thread
    int fI = t * 32 - base[t];        // F rows before this thread (enum order)
    #pragma unroll
    for (int i = 0; i < 32; ++i) {
        const int isA = (mask >> i) & 1;
        slotOf[t + 256 * i] = isA ? aB : (8191 - fI);
        aB += isA;
        fI += 1 - isA;
    }
}

// ---------------------------------------------------------------------------
// Kernel 1: L2-normalize -> bf16, scatter into K-chunk-BLOCKED G2:
//   byte addr = (slot>>7)*262144 + kc*8192 + (slot&127)*64 + inner
// Per (j,lane): 4 elems e0=j*256+lane*4 -> kc=j*8+(lane>>3), inner=(lane&7)*8.
// sqG/labG stay slot-indexed. posmin/negmin re-init in place (overlay) after
// consuming slotOf.  (R18-validated)
// ---------------------------------------------------------------------------
__global__ __launch_bounds__(256) void normalize_rows(
    const float* __restrict__ feat, const int* __restrict__ labels,
    int* slotOf /* aliases posmin */, unsigned* __restrict__ negmin,
    unsigned short* __restrict__ G, int* __restrict__ labG,
    float* __restrict__ sqG)
{
    const int wv = threadIdx.x >> 6, lane = threadIdx.x & 63;
    const int row = blockIdx.x * 4 + wv;

    const float4* src = (const float4*)(feat + (size_t)row * DIM);
    float4 v[4];
    float ss = 0.0f;
    #pragma unroll
    for (int j = 0; j < 4; ++j) {
        v[j] = src[j * 64 + lane];
        ss += v[j].x * v[j].x + v[j].y * v[j].y + v[j].z * v[j].z + v[j].w * v[j].w;
    }
    #pragma unroll
    for (int s = 32; s > 0; s >>= 1) ss += __shfl_xor(ss, s);
    const float inv = 1.0f / fmaxf(sqrtf(ss), 1e-12f);

    const int slot = slotOf[row];
    if (lane == 0) {
        ((unsigned*)slotOf)[row] = 0xFFFFFFFFu;   // posmin[row] = +inf bits
        negmin[row] = 0xFFFFFFFFu;
    }
    unsigned short ub[16];
    float ss2 = 0.0f;
    #pragma unroll
    for (int j = 0; j < 4; ++j) {
        const float f0 = v[j].x * inv, f1 = v[j].y * inv,
                    f2 = v[j].z * inv, f3 = v[j].w * inv;
        ub[j * 4 + 0] = f2bf_rne(f0); ub[j * 4 + 1] = f2bf_rne(f1);
        ub[j * 4 + 2] = f2bf_rne(f2); ub[j * 4 + 3] = f2bf_rne(f3);
        #pragma unroll
        for (int q = 0; q < 4; ++q) {
            const float fr = bf2f(ub[j * 4 + q]);
            ss2 += fr * fr;
        }
    }
    #pragma unroll
    for (int s = 32; s > 0; s >>= 1) ss2 += __shfl_xor(ss2, s);
    if (lane == 0) {
        sqG[slot]  = ss2;
        labG[slot] = labels[row];
    }
    // Blocked scatter: base of this slot's panel row.
    char* Gb = (char*)G;
    char* rowBase = Gb + (size_t)(slot >> 7) * 262144 + (size_t)(slot & 127) * 64
                       + (lane & 7) * 8;
    const int kc0 = lane >> 3;                 // 0..7
    #pragma unroll
    for (int j = 0; j < 4; ++j) {
        ushort4 pk;
        pk.x = ub[j * 4 + 0]; pk.y = ub[j * 4 + 1];
        pk.z = ub[j * 4 + 2]; pk.w = ub[j * 4 + 3];
        *(ushort4*)(rowBase + (size_t)(j * 8 + kc0) * 8192) = pk;
    }
}

// ---------------------------------------------------------------------------
// Kernel 2: persistent 128x128 tiles, 4 waves (each 64x64 via 4x4 of
// 16x16x32 bf16 MFMA), K=1024 in 32 steps of BK=32. (R18, 85.5us)
// Staging reads CONTIGUOUS 1 KiB per copy from the blocked layout:
//   A panel tx:      src = G2 + tx*262144      + step*8192 + c*1024 + lane*16
//   F panel (63-ty): src = G2 + (63-ty)*262144 + step*8192 + c*1024 + lane*16
// LDS row u holds: A local row u; F local row (127-u) [descending slots].
// F fragment reads use u = 127-x; epilogue F stats at slot = 8191 - local.
// XCD rectangle mapping retained.
// ---------------------------------------------------------------------------
__global__ __launch_bounds__(256) void tile_mindist(
    const unsigned short* __restrict__ G, const int* __restrict__ labG,
    const float* __restrict__ sqG, const unsigned* __restrict__ cnt,
    unsigned* __restrict__ posmin, unsigned* __restrict__ negmin)
{
    const int nA = (int)cnt[0];
    const int nF = B_ROWS - nA;
    const int nTA = (nA + 127) >> 7;
    const int nTF = (nF + 127) >> 7;

    // [buf][A=0/F=1][128 rows x 32 shorts (64 B, unpadded)] = 32,768 B
    __shared__ __align__(16) unsigned short S[2][2][128 * 32];

    const int t = threadIdx.x;
    const int lane = t & 63, w = t >> 6;
    const int wm = w >> 1, wn = w & 1;          // wave sub-tile coords (x64)
    const int l15 = lane & 15, quad = lane >> 4;

    // Staging: wave w owns chunks 2w, 2w+1 (16 rows x 64 B each, contiguous).
    const int ch0 = 2 * w;

    // Fragment read offsets (shorts), row stride 32 shorts.
    const int rdA  = (wm * 64 + l15) * 32 + quad * 8;
    const int rdF0 = ((1 - wn) * 64 + 15 - l15) * 32 + quad * 8;  // + (3-fn)*512

    const char* Gb = (const char*)G;

    // ---- per-XCD rectangle mapping (R16-validated algebra) ----
    const int xcd = blockIdx.x & 7;
    const int bx  = xcd & 1;                    // tx band (2)
    const int by  = xcd >> 1;                   // ty band (4)
    const int qa = nTA >> 1, ra = nTA & 1;
    const int sa = qa + ((bx < ra) ? 1 : 0);
    const int xa = bx * qa + ((bx < ra) ? bx : ra);
    const int qf = nTF >> 2, rf = nTF & 3;
    const int sf = qf + ((by < rf) ? 1 : 0);
    const int ya = by * qf + ((by < rf) ? by : rf);
    const int localN = sa * sf;
    const int j0 = blockIdx.x >> 3;             // 0..131
    const int jstride = (int)(gridDim.x >> 3);  // 132

    for (int j = j0; j < localN; j += jstride) {
        const int tx = xa + j / sf;             // slow: A-panel
        const int ty = ya + j % sf;             // fast: sweep F-band
        const int rowA0  = tx * 128;            // A slot base
        const int rowFl0 = ty * 128;            // F LOCAL base

        // Contiguous panel bases (blocked layout).
        const char* baseA = Gb + (size_t)tx * 262144 + (size_t)(ch0 * 1024) + lane * 16;
        const char* baseF = Gb + (size_t)(63 - ty) * 262144 + (size_t)(ch0 * 1024) + lane * 16;

        f32x4 acc[4][4] = {};

        // Prologue: stage K-chunk 0 into buffer 0.
        #pragma unroll
        for (int h = 0; h < 2; ++h) {
            async_copy16(baseA + h * 1024, &S[0][0][(ch0 + h) * 512]);
            async_copy16(baseF + h * 1024, &S[0][1][(ch0 + h) * 512]);
        }
        __syncthreads();                         // drains vmcnt (buf0 ready)

        #pragma unroll 4
        for (int step = 0; step < 32; ++step) {
            const int cur = step & 1;
            const int nb = cur ^ 1;
            if (step < 31) {                     // async-stage step+1 into nb
                const size_t off = (size_t)(step + 1) * 8192;
                #pragma unroll
                for (int h = 0; h < 2; ++h) {
                    async_copy16(baseA + off + h * 1024, &S[nb][0][(ch0 + h) * 512]);
                    async_copy16(baseF + off + h * 1024, &S[nb][1][(ch0 + h) * 512]);
                }
            }

            const unsigned short* pa = &S[cur][0][rdA];
            const unsigned short* pf = &S[cur][1][rdF0];
            bf16x8 a[4], b[4];
            #pragma unroll
            for (int fm = 0; fm < 4; ++fm) a[fm] = *(const bf16x8*)(pa + fm * 512);
            #pragma unroll
            for (int fn = 0; fn < 4; ++fn) b[fn] = *(const bf16x8*)(pf + (3 - fn) * 512);
            #pragma unroll
            for (int fm = 0; fm < 4; ++fm)
                #pragma unroll
                for (int fn = 0; fn < 4; ++fn)
                    acc[fm][fn] = __builtin_amdgcn_mfma_f32_16x16x32_bf16(
                        a[fm], b[fn], acc[fm][fn], 0, 0, 0);

            __syncthreads();   // one barrier: completes nb loads, frees cur
        }

        // Epilogue. C/D layout: col = lane&15 (F), row = quad*4+reg (A).
        const float INFV = __uint_as_float(0x7f800000u);
        float sqf[4]; int lf_[4]; bool vf[4];
        #pragma unroll
        for (int fn = 0; fn < 4; ++fn) {
            const int rfl = rowFl0 + wn * 64 + fn * 16 + l15;   // F local
            vf[fn] = rfl < nF;
            const int slotF = 8191 - rfl;       // always in [0,8191]
            sqf[fn] = sqG[slotF];
            lf_[fn] = labG[slotF];
        }
        #pragma unroll
        for (int fm = 0; fm < 4; ++fm) {
            #pragma unroll
            for (int r = 0; r < 4; ++r) {
                const int ra2 = rowA0 + wm * 64 + fm * 16 + quad * 4 + r;
                const bool va = ra2 < nA;
                const int rac = va ? ra2 : 0;
                const float sqa = sqG[rac];
                const int la_ = labG[rac];
                float pmin = INFV, nmin = INFV;
                #pragma unroll
                for (int fn = 0; fn < 4; ++fn) {
                    const float dd = fmaxf(sqa + sqf[fn] - 2.0f * acc[fm][fn][r], 0.0f);
                    if (vf[fn]) {
                        if (la_ == lf_[fn]) pmin = fminf(pmin, dd);
                        else                nmin = fminf(nmin, dd);
                    }
                }
                #pragma unroll
                for (int s = 1; s < 16; s <<= 1) {
                    pmin = fminf(pmin, __shfl_xor(pmin, s));
                    nmin = fminf(nmin, __shfl_xor(nmin, s));
                }
                if (l15 == 0 && va) {
                    if (pmin < INFV) atomicMin(&posmin[ra2], __float_as_uint(pmin));
                    if (nmin < INFV) atomicMin(&negmin[ra2], __float_as_uint(nmin));
                }
            }
        }
        __syncthreads();   // protect LDS before next tile's prologue writes
    }
}

// ---------------------------------------------------------------------------
// Kernel 3: hinge + sum/count with fused finalize via device-scope ticket.
// (R16/R18-validated)
// ---------------------------------------------------------------------------
__global__ __launch_bounds__(256) void reduce_loss(
    const unsigned* __restrict__ posmin, const unsigned* __restrict__ negmin,
    float* __restrict__ accum, unsigned* __restrict__ cnt,
    float* __restrict__ out)
{
    const int i = blockIdx.x * 256 + threadIdx.x;
    const unsigned up = posmin[i], un = negmin[i];
    float tl = 0.0f, c = 0.0f;
    if (up != 0xFFFFFFFFu && un != 0xFFFFFFFFu) {
        const float pd = sqrtf(__uint_as_float(up));
        const float nd = sqrtf(__uint_as_float(un));
        tl = fmaxf(pd - nd + 0.3f, 0.0f);
        c = 1.0f;
    }
    #pragma unroll
    for (int s = 32; s > 0; s >>= 1) {
        tl += __shfl_down(tl, s);
        c  += __shfl_down(c, s);
    }
    __shared__ float sb[8];
    const int lane = threadIdx.x & 63, w = threadIdx.x >> 6;
    if (lane == 0) { sb[w] = tl; sb[4 + w] = c; }
    __syncthreads();
    if (threadIdx.x == 0) {
        atomicAdd(&accum[0], sb[0] + sb[1] + sb[2] + sb[3]);
        atomicAdd(&accum[1], sb[4] + sb[5] + sb[6] + sb[7]);
        __threadfence();
        const unsigned ticket = atomicAdd(&cnt[1], 1u);
        if (ticket == 31u) {               // last of the 32 blocks
            __threadfence();
            const float s2 = atomicAdd(&accum[0], 0.0f);
            const float c2 = atomicAdd(&accum[1], 0.0f);
            out[0] = (c2 > 0.0f) ? s2 / fmaxf(c2, 1.0f) : 0.0f;
        }
    }
}

// ---------------------------------------------------------------------------
extern "C" void kernel_launch(void* const* d_in, const int* in_sizes, int n_in,
                              void* d_out, int out_size, void* d_ws, size_t ws_size,
                              hipStream_t stream) {
    const float* feat  = (const float*)d_in[0];
    const int* labels  = (const int*)d_in[1];
    const int* dom     = (const int*)d_in[2];
    float* out = (float*)d_out;

    char* ws = (char*)d_ws;
    // Workspace layout (bytes) — identical footprint to validated layout.
    // G is the K-chunk-BLOCKED G2: 64 panels x 256 KiB = 16,777,216 B.
    unsigned short* G   = (unsigned short*)(ws);                 // 16,777,216
    int*      labG      = (int*)(ws + 16777216);                 //     32,768
    float*    sqG       = (float*)(ws + 16809984);               //     32,768
    unsigned* posmin    = (unsigned*)(ws + 16842752);            //     32,768
    unsigned* negmin    = (unsigned*)(ws + 16875520);            //     32,768
    unsigned* cnt       = (unsigned*)(ws + 16908288);            //  8 (nA, ticket)
    float*    accum     = (float*)(ws + 16908296);               //  8 (sum, count)
    // slotOf OVERLAYS posmin: written by compute_slots, consumed and then
    // re-initialized to 0xFF in-place by normalize_rows (same-address order).
    int*      slotOf    = (int*)(ws + 16842752);

    compute_slots<<<1, 256, 0, stream>>>(dom, slotOf, cnt, accum);
    normalize_rows<<<B_ROWS / 4, 256, 0, stream>>>(feat, labels, slotOf,
                                                   negmin, G, labG, sqG);

    // Grid 1056 = 8 XCD groups x 132; per-XCD rectangle mapping in-kernel.
    tile_mindist<<<1056, 256, 0, stream>>>(G, labG, sqG, cnt, posmin, negmin);

    reduce_loss<<<B_ROWS / 256, 256, 0, stream>>>(posmin, negmin, accum, cnt, out);
}